// Round 7
// baseline (528.450 us; speedup 1.0000x reference)
//
#include <hip/hip_runtime.h>
#include <stdint.h>

#define NPOS 4096
#define NCH  256
#define NCI  128
#define NBATCH 4
#define NSPLIT 8
#define KRANGE (NPOS / NSPLIT)
#define LOG2E 1.44269504f

typedef float f32x16 __attribute__((ext_vector_type(16)));
typedef short short8 __attribute__((ext_vector_type(8)));

static __device__ __forceinline__ uint16_t f2bf(float f) {
  uint32_t u = __float_as_uint(f);
  u += 0x7fff + ((u >> 16) & 1);
  return (uint16_t)(u >> 16);
}
static __device__ __forceinline__ float bf2f(uint16_t h) {
  return __uint_as_float(((uint32_t)h) << 16);
}
static __device__ __forceinline__ uint32_t cvtpk(float a, float b) {
  uint32_t r;
  asm("v_cvt_pk_bf16_f32 %0, %1, %2" : "=v"(r) : "v"(a), "v"(b));
  return r;  // lo = bf16(a), hi = bf16(b)
}

// ---------------------------------------------------------------------------
// Prep: bf16 weights (theta block pre-scaled by LOG2E), fused BN scale/shift.
// ---------------------------------------------------------------------------
__global__ void prep_kernel(const float* __restrict__ w_theta,
                            const float* __restrict__ w_phi,
                            const float* __restrict__ w_g,
                            const float* __restrict__ w_out,
                            const float* __restrict__ b_theta,
                            const float* __restrict__ b_phi,
                            const float* __restrict__ b_g,
                            const float* __restrict__ b_out,
                            const float* __restrict__ bn_gamma,
                            const float* __restrict__ bn_beta,
                            const float* __restrict__ bn_mean,
                            const float* __restrict__ bn_var,
                            uint16_t* __restrict__ w_all,
                            uint16_t* __restrict__ w_out_bf,
                            float* __restrict__ b_all,
                            float* __restrict__ bn_scale,
                            float* __restrict__ bn_shift) {
  int idx = blockIdx.x * 256 + threadIdx.x;
  if (idx < 98304) {
    int o = idx >> 8;
    float v;
    if (o < 128)      v = w_theta[idx] * LOG2E;
    else if (o < 256) v = w_phi[idx - 32768];
    else              v = w_g[idx - 65536];
    w_all[idx] = f2bf(v);
  } else if (idx < 131072) {
    w_out_bf[idx - 98304] = f2bf(w_out[idx - 98304]);
  } else if (idx < 131456) {
    int o = idx - 131072;
    float v = (o < 128) ? b_theta[o] * LOG2E
            : (o < 256) ? b_phi[o - 128] : b_g[o - 256];
    b_all[o] = v;
  } else if (idx < 131712) {
    int o = idx - 131456;
    float s = bn_gamma[o] * rsqrtf(bn_var[o] + 1e-5f);
    bn_scale[o] = s;
    bn_shift[o] = (b_out[o] - bn_mean[o]) * s + bn_beta[o];
  }
}

// ---------------------------------------------------------------------------
// Projections via MFMA.  x tile staged to LDS as swizzled bf16 [n][c].
// ---------------------------------------------------------------------------
__global__ __launch_bounds__(512) void proj_kernel(
    const float* __restrict__ x, const uint16_t* __restrict__ w_all,
    const float* __restrict__ b_all,
    uint16_t* __restrict__ Q, uint16_t* __restrict__ K,
    uint16_t* __restrict__ Vt) {
  __shared__ __align__(16) uint16_t xs[64 * 256];  // byte(n,c)=n*512+((2c)^((n&7)<<4))
  int b = blockIdx.y;
  int n0 = blockIdx.x * 64;
  int tid = threadIdx.x;
  int lane = tid & 63;
  int wv = tid >> 6;                    // 0..7
  const float* xb = x + ((size_t)b * NCH) * NPOS + n0;
  #pragma unroll
  for (int i = 0; i < 16; i++) {
    int c = wv * 32 + i * 2;
    float v0 = xb[(size_t)c * NPOS + lane];
    float v1 = xb[(size_t)(c + 1) * NPOS + lane];
    uint32_t u = cvtpk(v0, v1);
    *(uint32_t*)((char*)xs + lane * 512 + ((2 * c) ^ ((lane & 7) << 4))) = u;
  }
  __syncthreads();

  int l31 = lane & 31;
  int h2 = lane >> 5;
  int nt = wv & 1;
  int og = wv >> 1;                     // 0..3
  int nl = nt * 32 + l31;
  int swz = (nl & 7) << 4;

  f32x16 accQ, accK, accV;
  #pragma unroll
  for (int i = 0; i < 16; i++) { accQ[i] = 0.f; accK[i] = 0.f; accV[i] = 0.f; }

  const uint16_t* wt = w_all + (size_t)(og * 32 + l31) * 256 + h2 * 8;
  const uint16_t* wp = wt + 128 * 256;
  const uint16_t* wg = wt + 256 * 256;

  #pragma unroll
  for (int kc = 0; kc < 16; kc++) {
    int c2 = kc * 32 + h2 * 16;         // 2*c0
    short8 xf = *(const short8*)((const char*)xs + nl * 512 + (c2 ^ swz));
    short8 a = *(const short8*)(wt + kc * 16);
    short8 p = *(const short8*)(wp + kc * 16);
    short8 g = *(const short8*)(wg + kc * 16);
    accQ = __builtin_amdgcn_mfma_f32_32x32x16_bf16(xf, a, accQ, 0, 0, 0);
    accK = __builtin_amdgcn_mfma_f32_32x32x16_bf16(xf, p, accK, 0, 0, 0);
    accV = __builtin_amdgcn_mfma_f32_32x32x16_bf16(g, xf, accV, 0, 0, 0);
  }

  int ocol = og * 32 + l31;
  float bq = b_all[ocol];
  float bk = b_all[128 + ocol];
  #pragma unroll
  for (int r = 0; r < 16; r++) {
    int n = nt * 32 + (r & 3) + 8 * (r >> 2) + 4 * h2;
    size_t row = ((size_t)b * NPOS + n0 + n) * NCI + ocol;
    Q[row] = f2bf(accQ[r] + bq);
    K[row] = f2bf(accK[r] + bk);
  }
  #pragma unroll
  for (int r = 0; r < 16; r++) {
    int ci = og * 32 + (r & 3) + 8 * (r >> 2) + 4 * h2;
    Vt[((size_t)b * NCI + ci) * NPOS + n0 + nt * 32 + l31] =
        f2bf(accV[r] + b_all[256 + ci]);
  }
}

// ---------------------------------------------------------------------------
// Flash attention: reg-staged LDS tiles (global->VGPR->swizzled ds_write),
// double-buffered; swapped-operand 32x32x16 MFMA; K-split=NSPLIT (=8 for
// 4 blocks/CU occupancy).  No max tracking (scores bounded).  P exchange via
// v_permlane32_swap_b32.  s_setprio(1) around the compute body (T5).
// ---------------------------------------------------------------------------
__global__ __launch_bounds__(256, 4) void attn_kernel(
    const uint16_t* __restrict__ Q, const uint16_t* __restrict__ K,
    const uint16_t* __restrict__ Vt, uint16_t* __restrict__ Ypart,
    float* __restrict__ Dpart) {
  __shared__ __align__(16) uint16_t kv[4 * 4096];  // K0 V0 K1 V1 (8KB each)
  uint16_t* Kb0 = kv;
  uint16_t* Vb0 = kv + 4096;
  uint16_t* Kb1 = kv + 8192;
  uint16_t* Vb1 = kv + 12288;

  int wg = blockIdx.x;                  // 0..1023
  int xcd = wg & 7;
  int slot = wg >> 3;                   // 0..127
  int b = xcd >> 1;                     // batch pinned per XCD pair
  int split = (xcd & 1) * 4 + (slot & 3);
  int qblk = slot >> 2;                 // 0..31
  int tid = threadIdx.x;
  int lane = tid & 63;
  int wv = tid >> 6;
  int q32 = lane & 31;
  int h2 = lane >> 5;
  int qb = qblk * 128 + wv * 32;

  const uint16_t* Qb = Q + ((size_t)b * NPOS + qb + q32) * NCI + h2 * 8;
  short8 qf[8];
  #pragma unroll
  for (int kc = 0; kc < 8; kc++)
    qf[kc] = *reinterpret_cast<const short8*>(Qb + kc * 16);

  const uint16_t* Kg = K + (size_t)b * NPOS * NCI;
  const uint16_t* Vg = Vt + (size_t)b * NCI * NPOS;

  // per-thread staging geometry (bytes pos -> element offsets)
  int posA = wv * 2048 + lane * 16;          // j=0 chunk
  int posB = posA + 1024;                    // j=1 chunk
  int rKA = posA >> 8, cKA = (posA >> 4) & 15;
  int rKB = posB >> 8, cKB = (posB >> 4) & 15;
  int wrKA = rKA * 128 + ((cKA ^ (rKA & 7)) << 3);
  int wrKB = rKB * 128 + ((cKB ^ (rKB & 7)) << 3);
  int gKA = rKA * NCI + cKA * 8;
  int gKB = rKB * NCI + cKB * 8;
  int ciA = posA >> 6, vsA = (posA >> 4) & 3;
  int ciB = posB >> 6, vsB = (posB >> 4) & 3;
  int wrVA = ciA * 32 + ((vsA ^ ((ciA >> 1) & 3)) << 3);
  int wrVB = ciB * 32 + ((vsB ^ ((ciB >> 1) & 3)) << 3);
  int gVA = ciA * NPOS + vsA * 8;
  int gVB = ciB * NPOS + vsB * 8;

  short8 stK0, stK1, stV0, stV1;

#define LOADR(MB)                                                             \
  {                                                                           \
    const uint16_t* kt = Kg + (size_t)(MB) * NCI;                             \
    const uint16_t* vt = Vg + (MB);                                           \
    stK0 = *(const short8*)(kt + gKA);                                        \
    stK1 = *(const short8*)(kt + gKB);                                        \
    stV0 = *(const short8*)(vt + gVA);                                        \
    stV1 = *(const short8*)(vt + gVB);                                        \
  }
#define WRITE(KB, VB)                                                         \
  {                                                                           \
    *(short8*)((KB) + wrKA) = stK0;                                           \
    *(short8*)((KB) + wrKB) = stK1;                                           \
    *(short8*)((VB) + wrVA) = stV0;                                           \
    *(short8*)((VB) + wrVB) = stV1;                                           \
  }

  f32x16 yacc[4];
  #pragma unroll
  for (int d = 0; d < 4; d++)
    #pragma unroll
    for (int i = 0; i < 16; i++) yacc[d][i] = 0.f;

  float den = 0.f;
  int m0 = split * KRANGE;

#define ATTN_BODY(KB, VB)                                                     \
  {                                                                           \
    short8 kf[8];                                                             \
    _Pragma("unroll")                                                         \
    for (int kc = 0; kc < 8; kc++) {                                          \
      int off = q32 * 128 + (((2 * kc + h2) ^ (q32 & 7)) << 3);               \
      kf[kc] = *(const short8*)((KB) + off);                                  \
    }                                                                         \
    short8 vf[2][4];                                                          \
    _Pragma("unroll")                                                         \
    for (int kc2 = 0; kc2 < 2; kc2++)                                         \
      _Pragma("unroll")                                                       \
      for (int dt = 0; dt < 4; dt++) {                                        \
        int ci = q32 + dt * 32;                                               \
        int off = ci * 32 + (((2 * kc2 + h2) ^ ((q32 >> 1) & 3)) << 3);       \
        vf[kc2][dt] = *(const short8*)((VB) + off);                           \
      }                                                                       \
    __builtin_amdgcn_s_setprio(1);                                            \
    f32x16 s;                                                                 \
    _Pragma("unroll")                                                         \
    for (int i = 0; i < 16; i++) s[i] = 0.f;                                  \
    _Pragma("unroll")                                                         \
    for (int kc = 0; kc < 8; kc++)                                            \
      s = __builtin_amdgcn_mfma_f32_32x32x16_bf16(kf[kc], qf[kc], s, 0, 0, 0);\
    _Pragma("unroll")                                                         \
    for (int i = 0; i < 16; i++) s[i] = exp2f(s[i]);                          \
    float r0 = (s[0] + s[1]) + (s[2] + s[3]);                                 \
    float r1 = (s[4] + s[5]) + (s[6] + s[7]);                                 \
    float r2 = (s[8] + s[9]) + (s[10] + s[11]);                               \
    float r3 = (s[12] + s[13]) + (s[14] + s[15]);                             \
    den += (r0 + r1) + (r2 + r3);                                             \
    uint32_t pk[8];                                                           \
    _Pragma("unroll")                                                         \
    for (int a2 = 0; a2 < 4; a2++) {                                          \
      pk[a2 * 2]     = cvtpk(s[4 * a2],     s[4 * a2 + 1]);                   \
      pk[a2 * 2 + 1] = cvtpk(s[4 * a2 + 2], s[4 * a2 + 3]);                   \
    }                                                                         \
    _Pragma("unroll")                                                         \
    for (int kc2 = 0; kc2 < 2; kc2++) {                                       \
      uint32_t A0 = pk[4 * kc2],     B0 = pk[4 * kc2 + 2];                    \
      uint32_t A1 = pk[4 * kc2 + 1], B1 = pk[4 * kc2 + 3];                    \
      asm("v_permlane32_swap_b32 %0, %1" : "+v"(A0), "+v"(B0));               \
      asm("v_permlane32_swap_b32 %0, %1" : "+v"(A1), "+v"(B1));               \
      union { short8 v; uint32_t u[4]; } pb;                                  \
      pb.u[0] = A0;                                                           \
      pb.u[1] = A1;                                                           \
      pb.u[2] = B0;                                                           \
      pb.u[3] = B1;                                                           \
      _Pragma("unroll")                                                       \
      for (int dt = 0; dt < 4; dt++)                                          \
        yacc[dt] = __builtin_amdgcn_mfma_f32_32x32x16_bf16(vf[kc2][dt], pb.v, \
                                                           yacc[dt], 0, 0, 0);\
    }                                                                         \
    __builtin_amdgcn_s_setprio(0);                                            \
  }

  // prologue: tile 0 -> buf0
  LOADR(m0)
  WRITE(Kb0, Vb0)
  __syncthreads();

  for (int it = 0; it < KRANGE / 64; it++) {
    int ms = it * 64;
    LOADR(m0 + ms + 32)                 // tile 2it+1 -> regs
    ATTN_BODY(Kb0, Vb0)                 // compute tile 2it
    WRITE(Kb1, Vb1)
    __syncthreads();
    int mn = m0 + ((ms + 64) & (KRANGE - 1));   // wrap: dummy on last iter
    LOADR(mn)                           // tile 2it+2 -> regs
    ATTN_BODY(Kb1, Vb1)                 // compute tile 2it+1
    WRITE(Kb0, Vb0)
    __syncthreads();
  }
#undef ATTN_BODY
#undef LOADR
#undef WRITE

  size_t pbase = ((size_t)(b * NSPLIT + split)) * NCI * NPOS;
  #pragma unroll
  for (int dt = 0; dt < 4; dt++)
    #pragma unroll
    for (int r = 0; r < 16; r++) {
      int drow = dt * 32 + (r & 3) + 8 * (r >> 2) + 4 * h2;
      Ypart[pbase + (size_t)drow * NPOS + qb + q32] = f2bf(yacc[dt][r]);
    }
  den += __shfl_xor(den, 32);
  if (h2 == 0) {
    size_t sbase = (size_t)(b * NSPLIT + split) * NPOS + qb + q32;
    Dpart[sbase] = den;
  }
}

// ---------------------------------------------------------------------------
// Epilogue: split-combine (vectorized short8 reads) -> ys LDS (bf16,
// swizzled) -> MFMA out-conv -> BN(scale,shift) + residual.
// ---------------------------------------------------------------------------
__global__ __launch_bounds__(512) void out_kernel(
    const uint16_t* __restrict__ Yp, const float* __restrict__ Dp,
    const uint16_t* __restrict__ w_out_bf,
    const float* __restrict__ bn_scale, const float* __restrict__ bn_shift,
    const float* __restrict__ x, float* __restrict__ out) {
  __shared__ __align__(16) uint16_t ys[64 * 128];  // byte(n,ci)=n*256+((2ci)^((n&7)<<4))
  __shared__ float rden_s[64];
  int b = blockIdx.y;
  int n0 = blockIdx.x * 64;
  int tid = threadIdx.x;

  if (tid < 64) {
    float den = 0.f;
    #pragma unroll
    for (int s2 = 0; s2 < NSPLIT; s2++)
      den += Dp[(size_t)(b * NSPLIT + s2) * NPOS + n0 + tid];
    rden_s[tid] = 1.f / den;
  }
  __syncthreads();

  {
    int ci = tid >> 2;                  // 0..127
    int g = tid & 3;                    // n-group of 16
    float sum[16];
    #pragma unroll
    for (int j = 0; j < 16; j++) sum[j] = 0.f;
    #pragma unroll
    for (int s2 = 0; s2 < NSPLIT; s2++) {
      const uint16_t* p =
          Yp + ((size_t)(b * NSPLIT + s2) * NCI + ci) * NPOS + n0 + g * 16;
      short8 v0 = *(const short8*)(p);
      short8 v1 = *(const short8*)(p + 8);
      #pragma unroll
      for (int j = 0; j < 8; j++) {
        sum[j]     += bf2f((uint16_t)v0[j]);
        sum[8 + j] += bf2f((uint16_t)v1[j]);
      }
    }
    #pragma unroll
    for (int j = 0; j < 16; j++) {
      int n = g * 16 + j;
      float v = sum[j] * rden_s[n];
      *(uint16_t*)((char*)ys + n * 256 + ((2 * ci) ^ ((n & 7) << 4))) = f2bf(v);
    }
  }
  __syncthreads();

  int lane = tid & 63;
  int wv = tid >> 6;
  int l31 = lane & 31;
  int h2 = lane >> 5;
  int og = wv;                          // 0..7
  f32x16 acc0, acc1;
  #pragma unroll
  for (int i = 0; i < 16; i++) { acc0[i] = 0.f; acc1[i] = 0.f; }
  const uint16_t* wo_base = w_out_bf + (size_t)(og * 32 + l31) * NCI + h2 * 8;
  int swz = (l31 & 7) << 4;
  #pragma unroll
  for (int kc = 0; kc < 8; kc++) {
    int c2 = kc * 32 + h2 * 16;
    short8 wo = *(const short8*)(wo_base + kc * 16);
    short8 y0 = *(const short8*)((const char*)ys + l31 * 256 + (c2 ^ swz));
    short8 y1 = *(const short8*)((const char*)ys + (32 + l31) * 256 + (c2 ^ swz));
    acc0 = __builtin_amdgcn_mfma_f32_32x32x16_bf16(wo, y0, acc0, 0, 0, 0);
    acc1 = __builtin_amdgcn_mfma_f32_32x32x16_bf16(wo, y1, acc1, 0, 0, 0);
  }
  #pragma unroll
  for (int r = 0; r < 16; r++) {
    int o = og * 32 + (r & 3) + 8 * (r >> 2) + 4 * h2;
    float sc = bn_scale[o];
    float sh = bn_shift[o];
    size_t base = ((size_t)b * NCH + o) * NPOS + n0;
    out[base + l31]      = fmaf(acc0[r], sc, sh) + x[base + l31];
    out[base + 32 + l31] = fmaf(acc1[r], sc, sh) + x[base + 32 + l31];
  }
}

// ---------------------------------------------------------------------------
extern "C" void kernel_launch(void* const* d_in, const int* in_sizes, int n_in,
                              void* d_out, int out_size, void* d_ws, size_t ws_size,
                              hipStream_t stream) {
  const float* x        = (const float*)d_in[0];
  const float* w_theta  = (const float*)d_in[1];
  const float* b_theta  = (const float*)d_in[2];
  const float* w_phi    = (const float*)d_in[3];
  const float* b_phi    = (const float*)d_in[4];
  const float* w_g      = (const float*)d_in[5];
  const float* b_g      = (const float*)d_in[6];
  const float* w_out    = (const float*)d_in[7];
  const float* b_out    = (const float*)d_in[8];
  const float* bn_gamma = (const float*)d_in[9];
  const float* bn_beta  = (const float*)d_in[10];
  const float* bn_mean  = (const float*)d_in[11];
  const float* bn_var   = (const float*)d_in[12];

  char* ws = (char*)d_ws;
  uint16_t* w_all    = (uint16_t*)ws;  ws += (size_t)384 * 256 * 2;
  uint16_t* w_out_bf = (uint16_t*)ws;  ws += (size_t)256 * 128 * 2;
  float* b_all       = (float*)ws;     ws += 2048;
  float* bn_scale    = (float*)ws;     ws += 1024;
  float* bn_shift    = (float*)ws;     ws += 1024;
  uint16_t* Q   = (uint16_t*)ws;  ws += (size_t)NBATCH * NPOS * NCI * 2;
  uint16_t* Kb  = (uint16_t*)ws;  ws += (size_t)NBATCH * NPOS * NCI * 2;
  uint16_t* Vt  = (uint16_t*)ws;  ws += (size_t)NBATCH * NCI * NPOS * 2;
  uint16_t* Yp  = (uint16_t*)ws;  ws += (size_t)NBATCH * NSPLIT * NCI * NPOS * 2;
  float* Dp     = (float*)ws;     ws += (size_t)NBATCH * NSPLIT * NPOS * 4;

  hipLaunchKernelGGL(prep_kernel, dim3(515), dim3(256), 0, stream,
                     w_theta, w_phi, w_g, w_out, b_theta, b_phi, b_g, b_out,
                     bn_gamma, bn_beta, bn_mean, bn_var,
                     w_all, w_out_bf, b_all, bn_scale, bn_shift);
  hipLaunchKernelGGL(proj_kernel, dim3(64, NBATCH), dim3(512), 0, stream,
                     x, w_all, b_all, Q, Kb, Vt);
  hipLaunchKernelGGL(attn_kernel, dim3(1024), dim3(256), 0, stream,
                     Q, Kb, Vt, Yp, Dp);
  hipLaunchKernelGGL(out_kernel, dim3(64, NBATCH), dim3(512), 0, stream,
                     Yp, Dp, w_out_bf, bn_scale, bn_shift, x, (float*)d_out);
}

// Round 8
// 157.986 us; speedup vs baseline: 3.3449x; 3.3449x over previous
//
#include <hip/hip_runtime.h>
#include <stdint.h>

#define NPOS 4096
#define NCH  256
#define NCI  128
#define NBATCH 4
#define NSPLIT 4
#define KRANGE (NPOS / NSPLIT)
#define LOG2E 1.44269504f

typedef float f32x16 __attribute__((ext_vector_type(16)));
typedef short short8 __attribute__((ext_vector_type(8)));

static __device__ __forceinline__ uint16_t f2bf(float f) {
  uint32_t u = __float_as_uint(f);
  u += 0x7fff + ((u >> 16) & 1);
  return (uint16_t)(u >> 16);
}
static __device__ __forceinline__ float bf2f(uint16_t h) {
  return __uint_as_float(((uint32_t)h) << 16);
}
static __device__ __forceinline__ uint32_t cvtpk(float a, float b) {
  uint32_t r;
  asm("v_cvt_pk_bf16_f32 %0, %1, %2" : "=v"(r) : "v"(a), "v"(b));
  return r;  // lo = bf16(a), hi = bf16(b)
}

// ---------------------------------------------------------------------------
// Prep: bf16 weights (theta block pre-scaled by LOG2E), fused BN scale/shift.
// ---------------------------------------------------------------------------
__global__ void prep_kernel(const float* __restrict__ w_theta,
                            const float* __restrict__ w_phi,
                            const float* __restrict__ w_g,
                            const float* __restrict__ w_out,
                            const float* __restrict__ b_theta,
                            const float* __restrict__ b_phi,
                            const float* __restrict__ b_g,
                            const float* __restrict__ b_out,
                            const float* __restrict__ bn_gamma,
                            const float* __restrict__ bn_beta,
                            const float* __restrict__ bn_mean,
                            const float* __restrict__ bn_var,
                            uint16_t* __restrict__ w_all,
                            uint16_t* __restrict__ w_out_bf,
                            float* __restrict__ b_all,
                            float* __restrict__ bn_scale,
                            float* __restrict__ bn_shift) {
  int idx = blockIdx.x * 256 + threadIdx.x;
  if (idx < 98304) {
    int o = idx >> 8;
    float v;
    if (o < 128)      v = w_theta[idx] * LOG2E;
    else if (o < 256) v = w_phi[idx - 32768];
    else              v = w_g[idx - 65536];
    w_all[idx] = f2bf(v);
  } else if (idx < 131072) {
    w_out_bf[idx - 98304] = f2bf(w_out[idx - 98304]);
  } else if (idx < 131456) {
    int o = idx - 131072;
    float v = (o < 128) ? b_theta[o] * LOG2E
            : (o < 256) ? b_phi[o - 128] : b_g[o - 256];
    b_all[o] = v;
  } else if (idx < 131712) {
    int o = idx - 131456;
    float s = bn_gamma[o] * rsqrtf(bn_var[o] + 1e-5f);
    bn_scale[o] = s;
    bn_shift[o] = (b_out[o] - bn_mean[o]) * s + bn_beta[o];
  }
}

// ---------------------------------------------------------------------------
// Projections via MFMA.  x tile staged to LDS as swizzled bf16 [n][c].
// ---------------------------------------------------------------------------
__global__ __launch_bounds__(512) void proj_kernel(
    const float* __restrict__ x, const uint16_t* __restrict__ w_all,
    const float* __restrict__ b_all,
    uint16_t* __restrict__ Q, uint16_t* __restrict__ K,
    uint16_t* __restrict__ Vt) {
  __shared__ __align__(16) uint16_t xs[64 * 256];  // byte(n,c)=n*512+((2c)^((n&7)<<4))
  int b = blockIdx.y;
  int n0 = blockIdx.x * 64;
  int tid = threadIdx.x;
  int lane = tid & 63;
  int wv = tid >> 6;                    // 0..7
  const float* xb = x + ((size_t)b * NCH) * NPOS + n0;
  #pragma unroll
  for (int i = 0; i < 16; i++) {
    int c = wv * 32 + i * 2;
    float v0 = xb[(size_t)c * NPOS + lane];
    float v1 = xb[(size_t)(c + 1) * NPOS + lane];
    uint32_t u = cvtpk(v0, v1);
    *(uint32_t*)((char*)xs + lane * 512 + ((2 * c) ^ ((lane & 7) << 4))) = u;
  }
  __syncthreads();

  int l31 = lane & 31;
  int h2 = lane >> 5;
  int nt = wv & 1;
  int og = wv >> 1;                     // 0..3
  int nl = nt * 32 + l31;
  int swz = (nl & 7) << 4;

  f32x16 accQ, accK, accV;
  #pragma unroll
  for (int i = 0; i < 16; i++) { accQ[i] = 0.f; accK[i] = 0.f; accV[i] = 0.f; }

  const uint16_t* wt = w_all + (size_t)(og * 32 + l31) * 256 + h2 * 8;
  const uint16_t* wp = wt + 128 * 256;
  const uint16_t* wg = wt + 256 * 256;

  #pragma unroll
  for (int kc = 0; kc < 16; kc++) {
    int c2 = kc * 32 + h2 * 16;         // 2*c0
    short8 xf = *(const short8*)((const char*)xs + nl * 512 + (c2 ^ swz));
    short8 a = *(const short8*)(wt + kc * 16);
    short8 p = *(const short8*)(wp + kc * 16);
    short8 g = *(const short8*)(wg + kc * 16);
    accQ = __builtin_amdgcn_mfma_f32_32x32x16_bf16(xf, a, accQ, 0, 0, 0);
    accK = __builtin_amdgcn_mfma_f32_32x32x16_bf16(xf, p, accK, 0, 0, 0);
    accV = __builtin_amdgcn_mfma_f32_32x32x16_bf16(g, xf, accV, 0, 0, 0);
  }

  int ocol = og * 32 + l31;
  float bq = b_all[ocol];
  float bk = b_all[128 + ocol];
  #pragma unroll
  for (int r = 0; r < 16; r++) {
    int n = nt * 32 + (r & 3) + 8 * (r >> 2) + 4 * h2;
    size_t row = ((size_t)b * NPOS + n0 + n) * NCI + ocol;
    Q[row] = f2bf(accQ[r] + bq);
    K[row] = f2bf(accK[r] + bk);
  }
  #pragma unroll
  for (int r = 0; r < 16; r++) {
    int ci = og * 32 + (r & 3) + 8 * (r >> 2) + 4 * h2;
    Vt[((size_t)b * NCI + ci) * NPOS + n0 + nt * 32 + l31] =
        f2bf(accV[r] + b_all[256 + ci]);
  }
}

// ---------------------------------------------------------------------------
// Flash attention: reg-staged LDS tiles (global->VGPR->swizzled ds_write),
// double-buffered; swapped-operand 32x32x16 MFMA; K-split=NSPLIT.
// No max tracking (scores bounded).  P exchange via v_permlane32_swap_b32.
// s_setprio(1) around the compute body.
// ---------------------------------------------------------------------------
__global__ __launch_bounds__(256, 2) void attn_kernel(
    const uint16_t* __restrict__ Q, const uint16_t* __restrict__ K,
    const uint16_t* __restrict__ Vt, uint16_t* __restrict__ Ypart,
    float* __restrict__ Dpart) {
  __shared__ __align__(16) uint16_t kv[4 * 4096];  // K0 V0 K1 V1 (8KB each)
  uint16_t* Kb0 = kv;
  uint16_t* Vb0 = kv + 4096;
  uint16_t* Kb1 = kv + 8192;
  uint16_t* Vb1 = kv + 12288;

  int wg = blockIdx.x;                  // 0..511
  int xcd = wg & 7;
  int slot = wg >> 3;
  int b = xcd >> 1;
  int split = (xcd & 1) * 2 + (slot & 1);
  int qblk = slot >> 1;
  int tid = threadIdx.x;
  int lane = tid & 63;
  int wv = tid >> 6;
  int q32 = lane & 31;
  int h2 = lane >> 5;
  int qb = qblk * 128 + wv * 32;

  const uint16_t* Qb = Q + ((size_t)b * NPOS + qb + q32) * NCI + h2 * 8;
  short8 qf[8];
  #pragma unroll
  for (int kc = 0; kc < 8; kc++)
    qf[kc] = *reinterpret_cast<const short8*>(Qb + kc * 16);

  const uint16_t* Kg = K + (size_t)b * NPOS * NCI;
  const uint16_t* Vg = Vt + (size_t)b * NCI * NPOS;

  // per-thread staging geometry (bytes pos -> element offsets)
  int posA = wv * 2048 + lane * 16;          // j=0 chunk
  int posB = posA + 1024;                    // j=1 chunk
  int rKA = posA >> 8, cKA = (posA >> 4) & 15;
  int rKB = posB >> 8, cKB = (posB >> 4) & 15;
  int wrKA = rKA * 128 + ((cKA ^ (rKA & 7)) << 3);
  int wrKB = rKB * 128 + ((cKB ^ (rKB & 7)) << 3);
  int gKA = rKA * NCI + cKA * 8;
  int gKB = rKB * NCI + cKB * 8;
  int ciA = posA >> 6, vsA = (posA >> 4) & 3;
  int ciB = posB >> 6, vsB = (posB >> 4) & 3;
  int wrVA = ciA * 32 + ((vsA ^ ((ciA >> 1) & 3)) << 3);
  int wrVB = ciB * 32 + ((vsB ^ ((ciB >> 1) & 3)) << 3);
  int gVA = ciA * NPOS + vsA * 8;
  int gVB = ciB * NPOS + vsB * 8;

  short8 stK0, stK1, stV0, stV1;

#define LOADR(MB)                                                             \
  {                                                                           \
    const uint16_t* kt = Kg + (size_t)(MB) * NCI;                             \
    const uint16_t* vt = Vg + (MB);                                           \
    stK0 = *(const short8*)(kt + gKA);                                        \
    stK1 = *(const short8*)(kt + gKB);                                        \
    stV0 = *(const short8*)(vt + gVA);                                        \
    stV1 = *(const short8*)(vt + gVB);                                        \
  }
#define WRITE(KB, VB)                                                         \
  {                                                                           \
    *(short8*)((KB) + wrKA) = stK0;                                           \
    *(short8*)((KB) + wrKB) = stK1;                                           \
    *(short8*)((VB) + wrVA) = stV0;                                           \
    *(short8*)((VB) + wrVB) = stV1;                                           \
  }

  f32x16 yacc[4];
  #pragma unroll
  for (int d = 0; d < 4; d++)
    #pragma unroll
    for (int i = 0; i < 16; i++) yacc[d][i] = 0.f;

  float den = 0.f;
  int m0 = split * KRANGE;

#define ATTN_BODY(KB, VB)                                                     \
  {                                                                           \
    short8 kf[8];                                                             \
    _Pragma("unroll")                                                         \
    for (int kc = 0; kc < 8; kc++) {                                          \
      int off = q32 * 128 + (((2 * kc + h2) ^ (q32 & 7)) << 3);               \
      kf[kc] = *(const short8*)((KB) + off);                                  \
    }                                                                         \
    short8 vf[2][4];                                                          \
    _Pragma("unroll")                                                         \
    for (int kc2 = 0; kc2 < 2; kc2++)                                         \
      _Pragma("unroll")                                                       \
      for (int dt = 0; dt < 4; dt++) {                                        \
        int ci = q32 + dt * 32;                                               \
        int off = ci * 32 + (((2 * kc2 + h2) ^ ((q32 >> 1) & 3)) << 3);       \
        vf[kc2][dt] = *(const short8*)((VB) + off);                           \
      }                                                                       \
    __builtin_amdgcn_s_setprio(1);                                            \
    f32x16 s;                                                                 \
    _Pragma("unroll")                                                         \
    for (int i = 0; i < 16; i++) s[i] = 0.f;                                  \
    _Pragma("unroll")                                                         \
    for (int kc = 0; kc < 8; kc++)                                            \
      s = __builtin_amdgcn_mfma_f32_32x32x16_bf16(kf[kc], qf[kc], s, 0, 0, 0);\
    _Pragma("unroll")                                                         \
    for (int i = 0; i < 16; i++) s[i] = exp2f(s[i]);                          \
    float r0 = (s[0] + s[1]) + (s[2] + s[3]);                                 \
    float r1 = (s[4] + s[5]) + (s[6] + s[7]);                                 \
    float r2 = (s[8] + s[9]) + (s[10] + s[11]);                               \
    float r3 = (s[12] + s[13]) + (s[14] + s[15]);                             \
    den += (r0 + r1) + (r2 + r3);                                             \
    uint32_t pk[8];                                                           \
    _Pragma("unroll")                                                         \
    for (int a2 = 0; a2 < 4; a2++) {                                          \
      pk[a2 * 2]     = cvtpk(s[4 * a2],     s[4 * a2 + 1]);                   \
      pk[a2 * 2 + 1] = cvtpk(s[4 * a2 + 2], s[4 * a2 + 3]);                   \
    }                                                                         \
    _Pragma("unroll")                                                         \
    for (int kc2 = 0; kc2 < 2; kc2++) {                                       \
      uint32_t A0 = pk[4 * kc2],     B0 = pk[4 * kc2 + 2];                    \
      uint32_t A1 = pk[4 * kc2 + 1], B1 = pk[4 * kc2 + 3];                    \
      asm("v_permlane32_swap_b32 %0, %1" : "+v"(A0), "+v"(B0));               \
      asm("v_permlane32_swap_b32 %0, %1" : "+v"(A1), "+v"(B1));               \
      union { short8 v; uint32_t u[4]; } pb;                                  \
      pb.u[0] = A0;                                                           \
      pb.u[1] = A1;                                                           \
      pb.u[2] = B0;                                                           \
      pb.u[3] = B1;                                                           \
      _Pragma("unroll")                                                       \
      for (int dt = 0; dt < 4; dt++)                                          \
        yacc[dt] = __builtin_amdgcn_mfma_f32_32x32x16_bf16(vf[kc2][dt], pb.v, \
                                                           yacc[dt], 0, 0, 0);\
    }                                                                         \
    __builtin_amdgcn_s_setprio(0);                                            \
  }

  // prologue: tile 0 -> buf0
  LOADR(m0)
  WRITE(Kb0, Vb0)
  __syncthreads();

  for (int it = 0; it < KRANGE / 64; it++) {
    int ms = it * 64;
    LOADR(m0 + ms + 32)                 // tile 2it+1 -> regs
    ATTN_BODY(Kb0, Vb0)                 // compute tile 2it
    WRITE(Kb1, Vb1)
    __syncthreads();
    int mn = m0 + ((ms + 64) & (KRANGE - 1));   // wrap: dummy on last iter
    LOADR(mn)                           // tile 2it+2 -> regs
    ATTN_BODY(Kb1, Vb1)                 // compute tile 2it+1
    WRITE(Kb0, Vb0)
    __syncthreads();
  }
#undef ATTN_BODY
#undef LOADR
#undef WRITE

  size_t pbase = ((size_t)(b * NSPLIT + split)) * NCI * NPOS;
  #pragma unroll
  for (int dt = 0; dt < 4; dt++)
    #pragma unroll
    for (int r = 0; r < 16; r++) {
      int drow = dt * 32 + (r & 3) + 8 * (r >> 2) + 4 * h2;
      Ypart[pbase + (size_t)drow * NPOS + qb + q32] = f2bf(yacc[dt][r]);
    }
  den += __shfl_xor(den, 32);
  if (h2 == 0) {
    size_t sbase = (size_t)(b * NSPLIT + split) * NPOS + qb + q32;
    Dpart[sbase] = den;
  }
}

// ---------------------------------------------------------------------------
// Epilogue: split-combine (vectorized short8 reads) -> ys LDS (bf16,
// swizzled) -> MFMA out-conv -> BN(scale,shift) + residual.
// ---------------------------------------------------------------------------
__global__ __launch_bounds__(512) void out_kernel(
    const uint16_t* __restrict__ Yp, const float* __restrict__ Dp,
    const uint16_t* __restrict__ w_out_bf,
    const float* __restrict__ bn_scale, const float* __restrict__ bn_shift,
    const float* __restrict__ x, float* __restrict__ out) {
  __shared__ __align__(16) uint16_t ys[64 * 128];  // byte(n,ci)=n*256+((2ci)^((n&7)<<4))
  __shared__ float rden_s[64];
  int b = blockIdx.y;
  int n0 = blockIdx.x * 64;
  int tid = threadIdx.x;

  if (tid < 64) {
    float den = 0.f;
    #pragma unroll
    for (int s2 = 0; s2 < NSPLIT; s2++)
      den += Dp[(size_t)(b * NSPLIT + s2) * NPOS + n0 + tid];
    rden_s[tid] = 1.f / den;
  }
  __syncthreads();

  {
    int ci = tid >> 2;                  // 0..127
    int g = tid & 3;                    // n-group of 16
    float sum[16];
    #pragma unroll
    for (int j = 0; j < 16; j++) sum[j] = 0.f;
    #pragma unroll
    for (int s2 = 0; s2 < NSPLIT; s2++) {
      const uint16_t* p =
          Yp + ((size_t)(b * NSPLIT + s2) * NCI + ci) * NPOS + n0 + g * 16;
      short8 v0 = *(const short8*)(p);
      short8 v1 = *(const short8*)(p + 8);
      #pragma unroll
      for (int j = 0; j < 8; j++) {
        sum[j]     += bf2f((uint16_t)v0[j]);
        sum[8 + j] += bf2f((uint16_t)v1[j]);
      }
    }
    #pragma unroll
    for (int j = 0; j < 16; j++) {
      int n = g * 16 + j;
      float v = sum[j] * rden_s[n];
      *(uint16_t*)((char*)ys + n * 256 + ((2 * ci) ^ ((n & 7) << 4))) = f2bf(v);
    }
  }
  __syncthreads();

  int lane = tid & 63;
  int wv = tid >> 6;
  int l31 = lane & 31;
  int h2 = lane >> 5;
  int og = wv;                          // 0..7
  f32x16 acc0, acc1;
  #pragma unroll
  for (int i = 0; i < 16; i++) { acc0[i] = 0.f; acc1[i] = 0.f; }
  const uint16_t* wo_base = w_out_bf + (size_t)(og * 32 + l31) * NCI + h2 * 8;
  int swz = (l31 & 7) << 4;
  #pragma unroll
  for (int kc = 0; kc < 8; kc++) {
    int c2 = kc * 32 + h2 * 16;
    short8 wo = *(const short8*)(wo_base + kc * 16);
    short8 y0 = *(const short8*)((const char*)ys + l31 * 256 + (c2 ^ swz));
    short8 y1 = *(const short8*)((const char*)ys + (32 + l31) * 256 + (c2 ^ swz));
    acc0 = __builtin_amdgcn_mfma_f32_32x32x16_bf16(wo, y0, acc0, 0, 0, 0);
    acc1 = __builtin_amdgcn_mfma_f32_32x32x16_bf16(wo, y1, acc1, 0, 0, 0);
  }
  #pragma unroll
  for (int r = 0; r < 16; r++) {
    int o = og * 32 + (r & 3) + 8 * (r >> 2) + 4 * h2;
    float sc = bn_scale[o];
    float sh = bn_shift[o];
    size_t base = ((size_t)b * NCH + o) * NPOS + n0;
    out[base + l31]      = fmaf(acc0[r], sc, sh) + x[base + l31];
    out[base + 32 + l31] = fmaf(acc1[r], sc, sh) + x[base + 32 + l31];
  }
}

// ---------------------------------------------------------------------------
extern "C" void kernel_launch(void* const* d_in, const int* in_sizes, int n_in,
                              void* d_out, int out_size, void* d_ws, size_t ws_size,
                              hipStream_t stream) {
  const float* x        = (const float*)d_in[0];
  const float* w_theta  = (const float*)d_in[1];
  const float* b_theta  = (const float*)d_in[2];
  const float* w_phi    = (const float*)d_in[3];
  const float* b_phi    = (const float*)d_in[4];
  const float* w_g      = (const float*)d_in[5];
  const float* b_g      = (const float*)d_in[6];
  const float* w_out    = (const float*)d_in[7];
  const float* b_out    = (const float*)d_in[8];
  const float* bn_gamma = (const float*)d_in[9];
  const float* bn_beta  = (const float*)d_in[10];
  const float* bn_mean  = (const float*)d_in[11];
  const float* bn_var   = (const float*)d_in[12];

  char* ws = (char*)d_ws;
  uint16_t* w_all    = (uint16_t*)ws;  ws += (size_t)384 * 256 * 2;
  uint16_t* w_out_bf = (uint16_t*)ws;  ws += (size_t)256 * 128 * 2;
  float* b_all       = (float*)ws;     ws += 2048;
  float* bn_scale    = (float*)ws;     ws += 1024;
  float* bn_shift    = (float*)ws;     ws += 1024;
  uint16_t* Q   = (uint16_t*)ws;  ws += (size_t)NBATCH * NPOS * NCI * 2;
  uint16_t* Kb  = (uint16_t*)ws;  ws += (size_t)NBATCH * NPOS * NCI * 2;
  uint16_t* Vt  = (uint16_t*)ws;  ws += (size_t)NBATCH * NCI * NPOS * 2;
  uint16_t* Yp  = (uint16_t*)ws;  ws += (size_t)NBATCH * NSPLIT * NCI * NPOS * 2;
  float* Dp     = (float*)ws;     ws += (size_t)NBATCH * NSPLIT * NPOS * 4;

  hipLaunchKernelGGL(prep_kernel, dim3(515), dim3(256), 0, stream,
                     w_theta, w_phi, w_g, w_out, b_theta, b_phi, b_g, b_out,
                     bn_gamma, bn_beta, bn_mean, bn_var,
                     w_all, w_out_bf, b_all, bn_scale, bn_shift);
  hipLaunchKernelGGL(proj_kernel, dim3(64, NBATCH), dim3(512), 0, stream,
                     x, w_all, b_all, Q, Kb, Vt);
  hipLaunchKernelGGL(attn_kernel, dim3(512), dim3(256), 0, stream,
                     Q, Kb, Vt, Yp, Dp);
  hipLaunchKernelGGL(out_kernel, dim3(64, NBATCH), dim3(512), 0, stream,
                     Yp, Dp, w_out_bf, bn_scale, bn_shift, x, (float*)d_out);
}